// Round 18
// baseline (360.641 us; speedup 1.0000x reference)
//
#include <hip/hip_runtime.h>

#define NN 100000
#define NE 1600000
#define HD 128
#define EPSI 1e-5f

using u32 = unsigned int;
using u16 = unsigned short;
using u8  = unsigned char;

typedef short bf16x8 __attribute__((ext_vector_type(8)));
typedef float f32x4  __attribute__((ext_vector_type(4)));
typedef float fltx2  __attribute__((ext_vector_type(2)));
typedef u32   u32x4  __attribute__((ext_vector_type(4)));
typedef u32   u32x2  __attribute__((ext_vector_type(2)));

constexpr int NRANGE      = 128;
constexpr int RSZ2        = 784;
constexpr int BINCAP      = 16384;
constexpr int PART_CHUNK4 = 1024;
constexpr int PART_GRID   = (NE / 4 + PART_CHUNK4 - 1) / PART_CHUNK4; // 391

// ---- bf16 helpers (storage bf16, arithmetic fp32) ----
__device__ inline float bflo(u32 u) { return __uint_as_float(u << 16); }
__device__ inline float bfhi(u32 u) { return __uint_as_float(u & 0xFFFF0000u); }
__device__ inline u16 f2bf(float f) {
    u32 u = __float_as_uint(f);
    u += 0x7FFFu + ((u >> 16) & 1u); // RNE
    return (u16)(u >> 16);
}
__device__ inline u32 pack2(float a, float b) {
    return (u32)f2bf(a) | ((u32)f2bf(b) << 16);
}

// ---- fp8 e4m3 (OCP) helpers: HW cvt if available, bit-twiddle fallback ----
#if __has_builtin(__builtin_amdgcn_cvt_pk_f32_fp8)
// packed accumulate: 4 cvt + 4 v_pk_add_f32 per 8 values
__device__ inline void add8fp8(fltx2* aa, u32x2 w) {
    aa[0] += __builtin_amdgcn_cvt_pk_f32_fp8(w.x, false);
    aa[1] += __builtin_amdgcn_cvt_pk_f32_fp8(w.x, true);
    aa[2] += __builtin_amdgcn_cvt_pk_f32_fp8(w.y, false);
    aa[3] += __builtin_amdgcn_cvt_pk_f32_fp8(w.y, true);
}
#else
__device__ inline float fp8d(u32 b) {
    const u32 em = b & 0x7Fu;
    const u32 s  = (b & 0x80u) << 24;
    if (em >= 8) return __uint_as_float(s | ((em << 20) + (120u << 23)));
    const float f = (float)em * 0.001953125f; // denormal: em * 2^-9
    return s ? -f : f;
}
__device__ inline void add8fp8(fltx2* aa, u32x2 w) {
    aa[0] += (fltx2){fp8d(w.x & 0xFFu), fp8d((w.x >> 8) & 0xFFu)};
    aa[1] += (fltx2){fp8d((w.x >> 16) & 0xFFu), fp8d(w.x >> 24)};
    aa[2] += (fltx2){fp8d(w.y & 0xFFu), fp8d((w.y >> 8) & 0xFFu)};
    aa[3] += (fltx2){fp8d((w.y >> 16) & 0xFFu), fp8d(w.y >> 24)};
}
#endif

#if __has_builtin(__builtin_amdgcn_cvt_pk_fp8_f32)
__device__ inline u32 pk4fp8(float x0, float x1, float x2, float x3) {
    u32 v = (u32)__builtin_amdgcn_cvt_pk_fp8_f32(x0, x1, 0, false);
    v = (u32)__builtin_amdgcn_cvt_pk_fp8_f32(x2, x3, (int)v, true);
    return v;
}
#else
__device__ inline u32 f2fp8(float f) {
    const u32 b = __float_as_uint(f);
    const u32 s = (b >> 24) & 0x80u;
    u32 v = b & 0x7FFFFFFFu;
    if (v >= 0x43E00000u) return s | 0x7Eu;   // clamp to 448
    if (v < (121u << 23)) return s;           // flush < 2^-6 to 0
    u32 r = v - (120u << 23);
    r = (r + 0x7FFFFu + ((r >> 20) & 1u)) >> 20; // RNE
    if (r > 0x7Eu) r = 0x7Eu;
    return s | r;
}
__device__ inline u32 pk4fp8(float x0, float x1, float x2, float x3) {
    return f2fp8(x0) | (f2fp8(x1) << 8) | (f2fp8(x2) << 16) | (f2fp8(x3) << 24);
}
#endif

// ---------------- CSR build: single-read 128-bin partition (u32-packed) ----------------

__global__ __launch_bounds__(256) void k_part(const int* __restrict__ src,
                                              const int* __restrict__ dst,
                                              int* __restrict__ binCur,
                                              u32* __restrict__ binbuf) {
    __shared__ int hist[NRANGE], base[NRANGE], curs[NRANGE];
    const int t  = threadIdx.x;
    const int c0 = blockIdx.x * PART_CHUNK4;
    if (t < NRANGE) { hist[t] = 0; curs[t] = 0; }
    __syncthreads();

    int4 ds[4], ss[4];
    bool ok[4];
#pragma unroll
    for (int i = 0; i < 4; ++i) {
        const int c = c0 + t + 256 * i;
        ok[i] = c < NE / 4;
        if (ok[i]) {
            ds[i] = reinterpret_cast<const int4*>(dst)[c];
            ss[i] = reinterpret_cast<const int4*>(src)[c];
        }
    }
#pragma unroll
    for (int i = 0; i < 4; ++i) {
        if (ok[i]) {
            atomicAdd(&hist[ds[i].x / RSZ2], 1);
            atomicAdd(&hist[ds[i].y / RSZ2], 1);
            atomicAdd(&hist[ds[i].z / RSZ2], 1);
            atomicAdd(&hist[ds[i].w / RSZ2], 1);
        }
    }
    __syncthreads();
    if (t < NRANGE && hist[t] > 0) base[t] = atomicAdd(&binCur[t], hist[t]);
    __syncthreads();

#pragma unroll
    for (int i = 0; i < 4; ++i) {
        if (ok[i]) {
            const int d[4] = {ds[i].x, ds[i].y, ds[i].z, ds[i].w};
            const int s[4] = {ss[i].x, ss[i].y, ss[i].z, ss[i].w};
#pragma unroll
            for (int j = 0; j < 4; ++j) {
                const int r  = d[j] / RSZ2;
                const int ld = d[j] - r * RSZ2;
                const int p  = base[r] + atomicAdd(&curs[r], 1);
                if (p < BINCAP)
                    binbuf[(size_t)r * BINCAP + p] = ((u32)s[j] << 10) | (u32)ld;
            }
        }
    }
}

// one block per range: LDS histogram -> LDS scans -> rp write -> ranked col fill
__global__ __launch_bounds__(1024) void k_fillL2(const int* __restrict__ binCur,
                                                 const u32* __restrict__ binbuf,
                                                 int* __restrict__ rp,
                                                 int* __restrict__ col) {
    __shared__ int hist[1024];
    __shared__ int sbuf[1024];
    __shared__ int bscan[NRANGE];
    const int b = blockIdx.x;
    const int t = threadIdx.x;

    hist[t] = 0;
    if (t < NRANGE) bscan[t] = min(binCur[t], BINCAP);
    __syncthreads();

    int bval = (t < NRANGE) ? bscan[t] : 0;
    for (int off = 1; off < NRANGE; off <<= 1) {
        const int o = (t >= off && t < NRANGE) ? bscan[t - off] : 0;
        __syncthreads();
        bval += o;
        if (t < NRANGE) bscan[t] = bval;
        __syncthreads();
    }
    const int binbase = (b == 0) ? 0 : bscan[b - 1];

    const int n = min(binCur[b], BINCAP);
    const u32* bin = binbuf + (size_t)b * BINCAP;
    for (int i = t; i < n; i += 1024)
        atomicAdd(&hist[bin[i] & 1023u], 1);
    __syncthreads();

    int v = hist[t];
    for (int off = 1; off < 1024; off <<= 1) {
        sbuf[t] = v;
        __syncthreads();
        if (t >= off) v += sbuf[t - off];
        __syncthreads();
    }
    const int excl = v - hist[t];
    const int rpv  = binbase + excl;
    const int idx  = b * RSZ2 + t;
    if (t < RSZ2 && idx < NN) rp[idx] = rpv;
    if (b == NRANGE - 1 && t == 0) rp[NN] = bscan[NRANGE - 1];
    __syncthreads();
    hist[t] = rpv;
    __syncthreads();

    for (int i = t; i < n; i += 1024) {
        const u32 e = bin[i];
        col[atomicAdd(&hist[e & 1023u], 1)] = (int)(e >> 10);
    }
}

// ---------------- weight prep: WT[n][k] = bf16(W[k][n]), 7 matrices ----------------

struct WTArgs { const float* w[7]; u16* o[7]; };

__global__ void k_wt(WTArgs a) {
    const int m = blockIdx.y;
    const int n = blockIdx.x;
    const int k = threadIdx.x;
    a.o[m][n * HD + k] = f2bf(a.w[m][k * HD + n]);
}

// ---------------- bf16 h -> fp8 h8 copy (once, after input layer) ----------------

__global__ __launch_bounds__(256) void k_h8(const u16* __restrict__ h,
                                            u32* __restrict__ h8w) {
    const size_t idx = (size_t)blockIdx.x * 256 + threadIdx.x; // one u32 = 4 fp8
    const uint2 v = reinterpret_cast<const uint2*>(h)[idx];
    h8w[idx] = pk4fp8(bflo(v.x), bfhi(v.x), bflo(v.y), bfhi(v.y));
}

// ---------------- mean aggregation (bf16 fallback, verified) ----------------

__device__ inline void acc8(float* a, u32x4 v) {
    a[0] += bflo(v.x); a[1] += bfhi(v.x);
    a[2] += bflo(v.y); a[3] += bfhi(v.y);
    a[4] += bflo(v.z); a[5] += bfhi(v.z);
    a[6] += bflo(v.w); a[7] += bfhi(v.w);
}

__global__ __launch_bounds__(256) void k_agg(const u16* __restrict__ h,
                                             const int* __restrict__ rp,
                                             const int* __restrict__ col,
                                             u16* __restrict__ mean) {
    const int lane = threadIdx.x & 63;
    const int node = blockIdx.x * 4 + (threadIdx.x >> 6);
    const int grp  = lane >> 4;
    const int li   = lane & 15;
    const int r0 = rp[node], r1 = rp[node + 1];
    const size_t lof = (size_t)li * 8;
    float a[8];
#pragma unroll
    for (int i = 0; i < 8; ++i) a[i] = 0.f;
    int e = r0 + grp;
    for (; e + 12 < r1; e += 16) {
        const int s0 = col[e], s1 = col[e + 4], s2 = col[e + 8], s3 = col[e + 12];
        const u32x4 v0 = *reinterpret_cast<const u32x4*>(&h[(size_t)s0 * HD + lof]);
        const u32x4 v1 = *reinterpret_cast<const u32x4*>(&h[(size_t)s1 * HD + lof]);
        const u32x4 v2 = *reinterpret_cast<const u32x4*>(&h[(size_t)s2 * HD + lof]);
        const u32x4 v3 = *reinterpret_cast<const u32x4*>(&h[(size_t)s3 * HD + lof]);
        acc8(a, v0); acc8(a, v1); acc8(a, v2); acc8(a, v3);
    }
    for (; e < r1; e += 4) {
        const u32x4 v = *reinterpret_cast<const u32x4*>(&h[(size_t)col[e] * HD + lof]);
        acc8(a, v);
    }
#pragma unroll
    for (int i = 0; i < 8; ++i) {
        a[i] += __shfl_xor(a[i], 16);
        a[i] += __shfl_xor(a[i], 32);
    }
    if (lane < 16) {
        const float inv = 1.0f / fmaxf((float)(r1 - r0), 1.0f);
        u32x4 o;
        o.x = pack2(a[0] * inv, a[1] * inv);
        o.y = pack2(a[2] * inv, a[3] * inv);
        o.z = pack2(a[4] * inv, a[5] * inv);
        o.w = pack2(a[6] * inv, a[7] * inv);
        __builtin_nontemporal_store(o, reinterpret_cast<u32x4*>(&mean[(size_t)node * HD + lof]));
    }
}

// ---------------- fp8 mean aggregation: contiguous per-group chunks, packed-f32 accum ----------------

__global__ __launch_bounds__(256) void k_agg8(const u32* __restrict__ h8,
                                              const int* __restrict__ rp,
                                              const int* __restrict__ col,
                                              u16* __restrict__ mean) {
    const int lane = threadIdx.x & 63;
    const int node = blockIdx.x * 4 + (threadIdx.x >> 6);
    const int grp  = lane >> 4;
    const int li   = lane & 15;                 // 8B chunk (8 fp8 cols) within 128B row
    const int r0 = rp[node], r1 = rp[node + 1];
    const int deg = r1 - r0;
    const int len = (deg + 3) >> 2;             // chunk per group
    int ge   = r0 + grp * len;
    int gend = ge + len;
    if (gend > r1) gend = r1;

    fltx2 aa[4];
#pragma unroll
    for (int i = 0; i < 4; ++i) aa[i] = (fltx2){0.f, 0.f};

    for (; ge + 3 < gend; ge += 4) {
        const int s0 = col[ge], s1 = col[ge + 1], s2 = col[ge + 2], s3 = col[ge + 3];
        const u32x2 v0 = *reinterpret_cast<const u32x2*>(&h8[(size_t)s0 * 32 + li * 2]);
        const u32x2 v1 = *reinterpret_cast<const u32x2*>(&h8[(size_t)s1 * 32 + li * 2]);
        const u32x2 v2 = *reinterpret_cast<const u32x2*>(&h8[(size_t)s2 * 32 + li * 2]);
        const u32x2 v3 = *reinterpret_cast<const u32x2*>(&h8[(size_t)s3 * 32 + li * 2]);
        add8fp8(aa, v0); add8fp8(aa, v1); add8fp8(aa, v2); add8fp8(aa, v3);
    }
    // tail (<=3 edges): issue all loads, then decode
    {
        const int rem = gend - ge;              // 0..3
        u32x2 v0, v1, v2;
        if (rem > 0) v0 = *reinterpret_cast<const u32x2*>(&h8[(size_t)col[ge] * 32 + li * 2]);
        if (rem > 1) v1 = *reinterpret_cast<const u32x2*>(&h8[(size_t)col[ge + 1] * 32 + li * 2]);
        if (rem > 2) v2 = *reinterpret_cast<const u32x2*>(&h8[(size_t)col[ge + 2] * 32 + li * 2]);
        if (rem > 0) add8fp8(aa, v0);
        if (rem > 1) add8fp8(aa, v1);
        if (rem > 2) add8fp8(aa, v2);
    }

    float a[8];
#pragma unroll
    for (int i = 0; i < 4; ++i) { a[i * 2] = aa[i].x; a[i * 2 + 1] = aa[i].y; }
#pragma unroll
    for (int i = 0; i < 8; ++i) {
        a[i] += __shfl_xor(a[i], 16);
        a[i] += __shfl_xor(a[i], 32);
    }
    if (lane < 16) {
        const float inv = 1.0f / fmaxf((float)deg, 1.0f);
        u32x4 o;
        o.x = pack2(a[0] * inv, a[1] * inv);
        o.y = pack2(a[2] * inv, a[3] * inv);
        o.z = pack2(a[4] * inv, a[5] * inv);
        o.w = pack2(a[6] * inv, a[7] * inv);
        __builtin_nontemporal_store(o, reinterpret_cast<u32x4*>(&mean[(size_t)node * HD + (size_t)li * 8]));
    }
}

// ---------------- MFMA GEMM: out = A1@W1 (+ A2@W2) + bias ----------------

template <int A1F32, int RELU, int STATS>
__global__ __launch_bounds__(256) void k_mgemm(
    const void* __restrict__ A1p, const u16* __restrict__ W1T,
    const u16* __restrict__ A2, const u16* __restrict__ W2T,
    const float* __restrict__ bias, u16* __restrict__ out,
    float* __restrict__ stats)
{
    __shared__ u32x4 Wlds[2048];
    const int t    = threadIdx.x;
    const int wv   = t >> 6;
    const int lane = t & 63;
    const int lid  = lane & 15;
    const int kseg = lane >> 4;
    const int row0 = blockIdx.x * 128 + wv * 32;

    f32x4 acc[2][8];
#pragma unroll
    for (int rf = 0; rf < 2; ++rf)
#pragma unroll
        for (int c = 0; c < 8; ++c) acc[rf][c] = (f32x4){0.f, 0.f, 0.f, 0.f};

    int  ar[2];
    bool rok[2];
#pragma unroll
    for (int rf = 0; rf < 2; ++rf) {
        ar[rf]  = row0 + rf * 16 + lid;
        rok[rf] = ar[rf] < NN;
    }

#pragma unroll
    for (int i = 0; i < 8; ++i) {
        const int g   = t + 256 * i;
        const int row = g >> 4;
        const int ch  = g & 15;
        Wlds[row * 16 + (ch ^ (row & 7))] = reinterpret_cast<const u32x4*>(W1T)[g];
    }
    u32x4 wreg[8];
    if (A2 != nullptr) {
#pragma unroll
        for (int i = 0; i < 8; ++i)
            wreg[i] = reinterpret_cast<const u32x4*>(W2T)[t + 256 * i];
    }

    bf16x8 af1[2][4], af2[2][4];
    if (A1F32) {
        const float* A = (const float*)A1p;
#pragma unroll
        for (int rf = 0; rf < 2; ++rf)
#pragma unroll
            for (int kk = 0; kk < 4; ++kk) {
                const int kof = kk * 32 + kseg * 8;
                if (rok[rf]) {
                    const float4 f0 = *reinterpret_cast<const float4*>(&A[(size_t)ar[rf] * HD + kof]);
                    const float4 f1 = *reinterpret_cast<const float4*>(&A[(size_t)ar[rf] * HD + kof + 4]);
                    af1[rf][kk][0] = (short)f2bf(f0.x); af1[rf][kk][1] = (short)f2bf(f0.y);
                    af1[rf][kk][2] = (short)f2bf(f0.z); af1[rf][kk][3] = (short)f2bf(f0.w);
                    af1[rf][kk][4] = (short)f2bf(f1.x); af1[rf][kk][5] = (short)f2bf(f1.y);
                    af1[rf][kk][6] = (short)f2bf(f1.z); af1[rf][kk][7] = (short)f2bf(f1.w);
                } else {
                    af1[rf][kk] = (bf16x8)0;
                }
            }
    } else {
        const u16* A = (const u16*)A1p;
#pragma unroll
        for (int rf = 0; rf < 2; ++rf)
#pragma unroll
            for (int kk = 0; kk < 4; ++kk) {
                const int kof = kk * 32 + kseg * 8;
                af1[rf][kk] = rok[rf]
                    ? *reinterpret_cast<const bf16x8*>(&A[(size_t)ar[rf] * HD + kof])
                    : (bf16x8)0;
            }
    }
    if (A2 != nullptr) {
#pragma unroll
        for (int rf = 0; rf < 2; ++rf)
#pragma unroll
            for (int kk = 0; kk < 4; ++kk) {
                const int kof = kk * 32 + kseg * 8;
                af2[rf][kk] = rok[rf]
                    ? *reinterpret_cast<const bf16x8*>(&A2[(size_t)ar[rf] * HD + kof])
                    : (bf16x8)0;
            }
    }

    __syncthreads();
#pragma unroll
    for (int kk = 0; kk < 4; ++kk) {
#pragma unroll
        for (int c = 0; c < 8; ++c) {
            const int brow = c * 16 + lid;
            const bf16x8 bf = *reinterpret_cast<const bf16x8*>(
                &Wlds[brow * 16 + ((kk * 4 + kseg) ^ (lid & 7))]);
#pragma unroll
            for (int rf = 0; rf < 2; ++rf)
                acc[rf][c] = __builtin_amdgcn_mfma_f32_16x16x32_bf16(af1[rf][kk], bf, acc[rf][c], 0, 0, 0);
        }
    }

    if (A2 != nullptr) {
        __syncthreads();
#pragma unroll
        for (int i = 0; i < 8; ++i) {
            const int g   = t + 256 * i;
            const int row = g >> 4;
            const int ch  = g & 15;
            Wlds[row * 16 + (ch ^ (row & 7))] = wreg[i];
        }
        __syncthreads();
#pragma unroll
        for (int kk = 0; kk < 4; ++kk) {
#pragma unroll
            for (int c = 0; c < 8; ++c) {
                const int brow = c * 16 + lid;
                const bf16x8 bf = *reinterpret_cast<const bf16x8*>(
                    &Wlds[brow * 16 + ((kk * 4 + kseg) ^ (lid & 7))]);
#pragma unroll
                for (int rf = 0; rf < 2; ++rf)
                    acc[rf][c] = __builtin_amdgcn_mfma_f32_16x16x32_bf16(af2[rf][kk], bf, acc[rf][c], 0, 0, 0);
            }
        }
    }

    float bv[8];
#pragma unroll
    for (int c = 0; c < 8; ++c) bv[c] = bias[c * 16 + lid];

    float sv[8], qv[8];
#pragma unroll
    for (int c = 0; c < 8; ++c) { sv[c] = 0.f; qv[c] = 0.f; }

#pragma unroll
    for (int rf = 0; rf < 2; ++rf) {
#pragma unroll
        for (int c = 0; c < 8; ++c) {
            const int colc = c * 16 + lid;
#pragma unroll
            for (int j = 0; j < 4; ++j) {
                const int rrow = row0 + rf * 16 + kseg * 4 + j;
                if (rrow < NN) {
                    float o = acc[rf][c][j] + bv[c];
                    if (RELU) o = fmaxf(o, 0.f);
                    out[(size_t)rrow * HD + colc] = f2bf(o);
                    sv[c] += o;
                    qv[c] += o * o;
                }
            }
        }
    }

    if constexpr (STATS) {
        __shared__ float ls[4][HD], lq[4][HD];
#pragma unroll
        for (int c = 0; c < 8; ++c) {
            sv[c] += __shfl_xor(sv[c], 16);
            sv[c] += __shfl_xor(sv[c], 32);
            qv[c] += __shfl_xor(qv[c], 16);
            qv[c] += __shfl_xor(qv[c], 32);
        }
        if (lane < 16) {
#pragma unroll
            for (int c = 0; c < 8; ++c) {
                ls[wv][c * 16 + lid] = sv[c];
                lq[wv][c * 16 + lid] = qv[c];
            }
        }
        __syncthreads();
        if (t < HD) {
            const float s = (ls[0][t] + ls[1][t]) + (ls[2][t] + ls[3][t]);
            atomicAdd(&stats[t], s);
        } else {
            const int j = t - HD;
            const float q = (lq[0][j] + lq[1][j]) + (lq[2][j] + lq[3][j]);
            atomicAdd(&stats[HD + j], q);
        }
    }
}

// ---------------- fused BN-finalize + relu + residual (+ classifier, + fp8 write) ----------------

template <int CLS>
__global__ __launch_bounds__(256) void k_apply(
    const u16* __restrict__ outb, const float* __restrict__ stats,
    const float* __restrict__ g, const float* __restrict__ bt,
    u16* __restrict__ hb, u32* __restrict__ h8w,
    const float* __restrict__ cw, const float* __restrict__ cb,
    float* __restrict__ logits)
{
    const int t = threadIdx.x;
    const size_t idx4 = (size_t)blockIdx.x * 256 + t;
    const int j = (int)(idx4 & 31) * 4;
    const float4 svv = *reinterpret_cast<const float4*>(&stats[j]);
    const float4 qvv = *reinterpret_cast<const float4*>(&stats[HD + j]);
    const float4 gv  = *reinterpret_cast<const float4*>(&g[j]);
    const float4 bv  = *reinterpret_cast<const float4*>(&bt[j]);
    const float invn = 1.0f / (float)NN;
    float sc[4], sh[4];
    {
        const float sa[4] = {svv.x, svv.y, svv.z, svv.w};
        const float qa[4] = {qvv.x, qvv.y, qvv.z, qvv.w};
        const float ga[4] = {gv.x, gv.y, gv.z, gv.w};
        const float ba[4] = {bv.x, bv.y, bv.z, bv.w};
#pragma unroll
        for (int i = 0; i < 4; ++i) {
            const float mean = sa[i] * invn;
            const float var  = qa[i] * invn - mean * mean;
            sc[i] = ga[i] * rsqrtf(var + EPSI);
            sh[i] = ba[i] - mean * sc[i];
        }
    }
    const uint2 o  = reinterpret_cast<const uint2*>(outb)[idx4];
    const uint2 hv = reinterpret_cast<const uint2*>(hb)[idx4];
    const float r0 = fmaxf(bflo(o.x) * sc[0] + sh[0], 0.f) + bflo(hv.x);
    const float r1 = fmaxf(bfhi(o.x) * sc[1] + sh[1], 0.f) + bfhi(hv.x);
    const float r2 = fmaxf(bflo(o.y) * sc[2] + sh[2], 0.f) + bflo(hv.y);
    const float r3 = fmaxf(bfhi(o.y) * sc[3] + sh[3], 0.f) + bfhi(hv.y);
    reinterpret_cast<uint2*>(hb)[idx4] = make_uint2(pack2(r0, r1), pack2(r2, r3));
    if (h8w != nullptr)
        h8w[idx4] = pk4fp8(r0, r1, r2, r3);

    if constexpr (CLS) {
        const float4 w01 = *reinterpret_cast<const float4*>(&cw[j * 2]);
        const float4 w23 = *reinterpret_cast<const float4*>(&cw[j * 2 + 4]);
        float p0 = r0 * w01.x + r1 * w01.z + r2 * w23.x + r3 * w23.z;
        float p1 = r0 * w01.y + r1 * w01.w + r2 * w23.y + r3 * w23.w;
#pragma unroll
        for (int off = 1; off <= 16; off <<= 1) {
            p0 += __shfl_xor(p0, off);
            p1 += __shfl_xor(p1, off);
        }
        if ((t & 31) == 0) {
            const size_t row = idx4 >> 5;
            logits[row * 2 + 0] = p0 + cb[0];
            logits[row * 2 + 1] = p1 + cb[1];
        }
    }
}

// ---------------- launch ----------------

extern "C" void kernel_launch(void* const* d_in, const int* in_sizes, int n_in,
                              void* d_out, int out_size, void* d_ws, size_t ws_size,
                              hipStream_t stream) {
    const float* x     = (const float*)d_in[0];
    const int*   ei    = (const int*)d_in[1];
    const float* in_w  = (const float*)d_in[2];
    const float* in_b  = (const float*)d_in[3];
    const float* cls_w = (const float*)d_in[4];
    const float* cls_b = (const float*)d_in[5];
    const float* blk_w[3][5];
    for (int bidx = 0; bidx < 3; ++bidx)
        for (int k = 0; k < 5; ++k)
            blk_w[bidx][k] = (const float*)d_in[6 + bidx * 5 + k];

    const int* src = ei;
    const int* dst = ei + NE;

    size_t off = 0;
    auto alloc = [&](size_t bytes) {
        void* p = (char*)d_ws + off;
        off += (bytes + 255) & ~(size_t)255;
        return p;
    };
    u16*   h      = (u16*)alloc((size_t)NN * HD * 2);   // 25.6 MB
    u16*   tmp    = (u16*)alloc((size_t)NN * HD * 2);   // 25.6 MB (binbuf, then mean/pre-BN out)
    int*   rp     = (int*)alloc((size_t)(NN + 1) * 4);
    int*   col    = (int*)alloc((size_t)NE * 4);        // 6.4 MB
    u16*   wtb    = (u16*)alloc((size_t)7 * HD * HD * 2);
    const size_t off_z = off;
    float* stats  = (float*)alloc((size_t)3 * 256 * 4);
    int*   binCur = (int*)alloc((size_t)NRANGE * 4);
    const size_t zspan = off - off_z;
    u32*   h8     = (u32*)alloc((size_t)NN * HD);       // 12.8 MB fp8 copy
    const bool useFp8 = (ws_size >= off);
    u32*   binbuf = (u32*)tmp;
    (void)n_in; (void)in_sizes; (void)out_size;

    (void)hipMemsetAsync(stats, 0, zspan, stream);

    WTArgs wa;
    wa.w[0] = in_w;
    for (int bidx = 0; bidx < 3; ++bidx) {
        wa.w[1 + bidx * 2] = blk_w[bidx][0];
        wa.w[2 + bidx * 2] = blk_w[bidx][2];
    }
    for (int m = 0; m < 7; ++m) wa.o[m] = wtb + (size_t)m * HD * HD;
    k_wt<<<dim3(HD, 7), HD, 0, stream>>>(wa);

    // CSR build
    k_part<<<PART_GRID, 256, 0, stream>>>(src, dst, binCur, binbuf);
    k_fillL2<<<NRANGE, 1024, 0, stream>>>(binCur, binbuf, rp, col);

    const int gemm_grid  = (NN + 127) / 128; // 782
    const int apply_grid = NN * 32 / 256;    // 12500

    // input layer: h = relu(x @ in_w + in_b)
    k_mgemm<1, 1, 0><<<gemm_grid, 256, 0, stream>>>(x, wtb, nullptr, nullptr, in_b, h, nullptr);
    if (useFp8)
        k_h8<<<apply_grid, 256, 0, stream>>>(h, h8);

    for (int bidx = 0; bidx < 3; ++bidx) {
        const u16* lwT = wtb + (size_t)(1 + bidx * 2) * HD * HD;
        const u16* rwT = wtb + (size_t)(2 + bidx * 2) * HD * HD;
        const float* lb = blk_w[bidx][1];
        const float* g  = blk_w[bidx][3];
        const float* bt = blk_w[bidx][4];
        float* st = stats + bidx * 256;

        if (useFp8)
            k_agg8<<<NN / 4, 256, 0, stream>>>(h8, rp, col, tmp);
        else
            k_agg<<<NN / 4, 256, 0, stream>>>(h, rp, col, tmp);

        k_mgemm<0, 0, 1><<<gemm_grid, 256, 0, stream>>>(tmp, lwT, h, rwT, lb, tmp, st);

        u32* h8out = (useFp8 && bidx < 2) ? h8 : nullptr;
        if (bidx < 2)
            k_apply<0><<<apply_grid, 256, 0, stream>>>(tmp, st, g, bt, h, h8out,
                                                       nullptr, nullptr, nullptr);
        else
            k_apply<1><<<apply_grid, 256, 0, stream>>>(tmp, st, g, bt, h, h8out,
                                                       cls_w, cls_b, (float*)d_out);
    }
}

// Round 19
// 357.200 us; speedup vs baseline: 1.0096x; 1.0096x over previous
//
#include <hip/hip_runtime.h>

#define NN 100000
#define NE 1600000
#define HD 128
#define EPSI 1e-5f

using u32 = unsigned int;
using u16 = unsigned short;
using u8  = unsigned char;

typedef short bf16x8 __attribute__((ext_vector_type(8)));
typedef float f32x4  __attribute__((ext_vector_type(4)));
typedef float fltx2  __attribute__((ext_vector_type(2)));
typedef u32   u32x4  __attribute__((ext_vector_type(4)));
typedef u32   u32x2  __attribute__((ext_vector_type(2)));

constexpr int NRANGE      = 128;
constexpr int RSZ2        = 784;
constexpr int BINCAP      = 16384;
constexpr int PART_CHUNK4 = 1024;
constexpr int PART_GRID   = (NE / 4 + PART_CHUNK4 - 1) / PART_CHUNK4; // 391

// ---- bf16 helpers (storage bf16, arithmetic fp32) ----
__device__ inline float bflo(u32 u) { return __uint_as_float(u << 16); }
__device__ inline float bfhi(u32 u) { return __uint_as_float(u & 0xFFFF0000u); }
__device__ inline u16 f2bf(float f) {
    u32 u = __float_as_uint(f);
    u += 0x7FFFu + ((u >> 16) & 1u); // RNE
    return (u16)(u >> 16);
}
__device__ inline u32 pack2(float a, float b) {
    return (u32)f2bf(a) | ((u32)f2bf(b) << 16);
}

// ---- fp8 e4m3 (OCP) helpers: HW cvt if available, bit-twiddle fallback ----
#if __has_builtin(__builtin_amdgcn_cvt_pk_f32_fp8)
__device__ inline void add8fp8(fltx2* aa, u32x2 w) {
    aa[0] += __builtin_amdgcn_cvt_pk_f32_fp8(w.x, false);
    aa[1] += __builtin_amdgcn_cvt_pk_f32_fp8(w.x, true);
    aa[2] += __builtin_amdgcn_cvt_pk_f32_fp8(w.y, false);
    aa[3] += __builtin_amdgcn_cvt_pk_f32_fp8(w.y, true);
}
#else
__device__ inline float fp8d(u32 b) {
    const u32 em = b & 0x7Fu;
    const u32 s  = (b & 0x80u) << 24;
    if (em >= 8) return __uint_as_float(s | ((em << 20) + (120u << 23)));
    const float f = (float)em * 0.001953125f; // denormal: em * 2^-9
    return s ? -f : f;
}
__device__ inline void add8fp8(fltx2* aa, u32x2 w) {
    aa[0] += (fltx2){fp8d(w.x & 0xFFu), fp8d((w.x >> 8) & 0xFFu)};
    aa[1] += (fltx2){fp8d((w.x >> 16) & 0xFFu), fp8d(w.x >> 24)};
    aa[2] += (fltx2){fp8d(w.y & 0xFFu), fp8d((w.y >> 8) & 0xFFu)};
    aa[3] += (fltx2){fp8d((w.y >> 16) & 0xFFu), fp8d(w.y >> 24)};
}
#endif

#if __has_builtin(__builtin_amdgcn_cvt_pk_fp8_f32)
__device__ inline u32 pk4fp8(float x0, float x1, float x2, float x3) {
    u32 v = (u32)__builtin_amdgcn_cvt_pk_fp8_f32(x0, x1, 0, false);
    v = (u32)__builtin_amdgcn_cvt_pk_fp8_f32(x2, x3, (int)v, true);
    return v;
}
#else
__device__ inline u32 f2fp8(float f) {
    const u32 b = __float_as_uint(f);
    const u32 s = (b >> 24) & 0x80u;
    u32 v = b & 0x7FFFFFFFu;
    if (v >= 0x43E00000u) return s | 0x7Eu;   // clamp to 448
    if (v < (121u << 23)) return s;           // flush < 2^-6 to 0
    u32 r = v - (120u << 23);
    r = (r + 0x7FFFFu + ((r >> 20) & 1u)) >> 20; // RNE
    if (r > 0x7Eu) r = 0x7Eu;
    return s | r;
}
__device__ inline u32 pk4fp8(float x0, float x1, float x2, float x3) {
    return f2fp8(x0) | (f2fp8(x1) << 8) | (f2fp8(x2) << 16) | (f2fp8(x3) << 24);
}
#endif

// ---------------- CSR build: single-read 128-bin partition (u32-packed) ----------------

__global__ __launch_bounds__(256) void k_part(const int* __restrict__ src,
                                              const int* __restrict__ dst,
                                              int* __restrict__ binCur,
                                              u32* __restrict__ binbuf) {
    __shared__ int hist[NRANGE], base[NRANGE], curs[NRANGE];
    const int t  = threadIdx.x;
    const int c0 = blockIdx.x * PART_CHUNK4;
    if (t < NRANGE) { hist[t] = 0; curs[t] = 0; }
    __syncthreads();

    int4 ds[4], ss[4];
    bool ok[4];
#pragma unroll
    for (int i = 0; i < 4; ++i) {
        const int c = c0 + t + 256 * i;
        ok[i] = c < NE / 4;
        if (ok[i]) {
            ds[i] = reinterpret_cast<const int4*>(dst)[c];
            ss[i] = reinterpret_cast<const int4*>(src)[c];
        }
    }
#pragma unroll
    for (int i = 0; i < 4; ++i) {
        if (ok[i]) {
            atomicAdd(&hist[ds[i].x / RSZ2], 1);
            atomicAdd(&hist[ds[i].y / RSZ2], 1);
            atomicAdd(&hist[ds[i].z / RSZ2], 1);
            atomicAdd(&hist[ds[i].w / RSZ2], 1);
        }
    }
    __syncthreads();
    if (t < NRANGE && hist[t] > 0) base[t] = atomicAdd(&binCur[t], hist[t]);
    __syncthreads();

#pragma unroll
    for (int i = 0; i < 4; ++i) {
        if (ok[i]) {
            const int d[4] = {ds[i].x, ds[i].y, ds[i].z, ds[i].w};
            const int s[4] = {ss[i].x, ss[i].y, ss[i].z, ss[i].w};
#pragma unroll
            for (int j = 0; j < 4; ++j) {
                const int r  = d[j] / RSZ2;
                const int ld = d[j] - r * RSZ2;
                const int p  = base[r] + atomicAdd(&curs[r], 1);
                if (p < BINCAP)
                    binbuf[(size_t)r * BINCAP + p] = ((u32)s[j] << 10) | (u32)ld;
            }
        }
    }
}

// one block per range: LDS histogram -> LDS scans -> rp write -> ranked col fill
__global__ __launch_bounds__(1024) void k_fillL2(const int* __restrict__ binCur,
                                                 const u32* __restrict__ binbuf,
                                                 int* __restrict__ rp,
                                                 int* __restrict__ col) {
    __shared__ int hist[1024];
    __shared__ int sbuf[1024];
    __shared__ int bscan[NRANGE];
    const int b = blockIdx.x;
    const int t = threadIdx.x;

    hist[t] = 0;
    if (t < NRANGE) bscan[t] = min(binCur[t], BINCAP);
    __syncthreads();

    int bval = (t < NRANGE) ? bscan[t] : 0;
    for (int off = 1; off < NRANGE; off <<= 1) {
        const int o = (t >= off && t < NRANGE) ? bscan[t - off] : 0;
        __syncthreads();
        bval += o;
        if (t < NRANGE) bscan[t] = bval;
        __syncthreads();
    }
    const int binbase = (b == 0) ? 0 : bscan[b - 1];

    const int n = min(binCur[b], BINCAP);
    const u32* bin = binbuf + (size_t)b * BINCAP;
    for (int i = t; i < n; i += 1024)
        atomicAdd(&hist[bin[i] & 1023u], 1);
    __syncthreads();

    int v = hist[t];
    for (int off = 1; off < 1024; off <<= 1) {
        sbuf[t] = v;
        __syncthreads();
        if (t >= off) v += sbuf[t - off];
        __syncthreads();
    }
    const int excl = v - hist[t];
    const int rpv  = binbase + excl;
    const int idx  = b * RSZ2 + t;
    if (t < RSZ2 && idx < NN) rp[idx] = rpv;
    if (b == NRANGE - 1 && t == 0) rp[NN] = bscan[NRANGE - 1];
    __syncthreads();
    hist[t] = rpv;
    __syncthreads();

    for (int i = t; i < n; i += 1024) {
        const u32 e = bin[i];
        col[atomicAdd(&hist[e & 1023u], 1)] = (int)(e >> 10);
    }
}

// ---------------- weight prep (+ zero stats/binCur: replaces a memset dispatch) ----------------

struct WTArgs { const float* w[7]; u16* o[7]; };

__global__ void k_wt(WTArgs a, float* __restrict__ stats, int* __restrict__ binCur) {
    const int m = blockIdx.y;
    const int n = blockIdx.x;
    const int k = threadIdx.x;
    if (m == 0 && n < 8) {
        const int zi = n * 128 + k;       // 0..1023
        if (zi < 3 * 256) stats[zi] = 0.f;
        else if (zi < 3 * 256 + NRANGE) binCur[zi - 3 * 256] = 0;
    }
    a.o[m][n * HD + k] = f2bf(a.w[m][k * HD + n]);
}

// ---------------- bf16 h -> fp8 h8 copy (once, after input layer) ----------------

__global__ __launch_bounds__(256) void k_h8(const u16* __restrict__ h,
                                            u32* __restrict__ h8w) {
    const size_t idx = (size_t)blockIdx.x * 256 + threadIdx.x; // one u32 = 4 fp8
    const uint2 v = reinterpret_cast<const uint2*>(h)[idx];
    h8w[idx] = pk4fp8(bflo(v.x), bfhi(v.x), bflo(v.y), bfhi(v.y));
}

// ---------------- mean aggregation (bf16 fallback, verified) ----------------

__device__ inline void acc8(float* a, u32x4 v) {
    a[0] += bflo(v.x); a[1] += bfhi(v.x);
    a[2] += bflo(v.y); a[3] += bfhi(v.y);
    a[4] += bflo(v.z); a[5] += bfhi(v.z);
    a[6] += bflo(v.w); a[7] += bfhi(v.w);
}

__global__ __launch_bounds__(256) void k_agg(const u16* __restrict__ h,
                                             const int* __restrict__ rp,
                                             const int* __restrict__ col,
                                             u16* __restrict__ mean) {
    const int lane = threadIdx.x & 63;
    const int node = blockIdx.x * 4 + (threadIdx.x >> 6);
    const int grp  = lane >> 4;
    const int li   = lane & 15;
    const int r0 = rp[node], r1 = rp[node + 1];
    const size_t lof = (size_t)li * 8;
    float a[8];
#pragma unroll
    for (int i = 0; i < 8; ++i) a[i] = 0.f;
    int e = r0 + grp;
    for (; e + 12 < r1; e += 16) {
        const int s0 = col[e], s1 = col[e + 4], s2 = col[e + 8], s3 = col[e + 12];
        const u32x4 v0 = *reinterpret_cast<const u32x4*>(&h[(size_t)s0 * HD + lof]);
        const u32x4 v1 = *reinterpret_cast<const u32x4*>(&h[(size_t)s1 * HD + lof]);
        const u32x4 v2 = *reinterpret_cast<const u32x4*>(&h[(size_t)s2 * HD + lof]);
        const u32x4 v3 = *reinterpret_cast<const u32x4*>(&h[(size_t)s3 * HD + lof]);
        acc8(a, v0); acc8(a, v1); acc8(a, v2); acc8(a, v3);
    }
    for (; e < r1; e += 4) {
        const u32x4 v = *reinterpret_cast<const u32x4*>(&h[(size_t)col[e] * HD + lof]);
        acc8(a, v);
    }
#pragma unroll
    for (int i = 0; i < 8; ++i) {
        a[i] += __shfl_xor(a[i], 16);
        a[i] += __shfl_xor(a[i], 32);
    }
    if (lane < 16) {
        const float inv = 1.0f / fmaxf((float)(r1 - r0), 1.0f);
        u32x4 o;
        o.x = pack2(a[0] * inv, a[1] * inv);
        o.y = pack2(a[2] * inv, a[3] * inv);
        o.z = pack2(a[4] * inv, a[5] * inv);
        o.w = pack2(a[6] * inv, a[7] * inv);
        __builtin_nontemporal_store(o, reinterpret_cast<u32x4*>(&mean[(size_t)node * HD + lof]));
    }
}

// ---------------- fp8 mean aggregation: contiguous chunks, 8/4-deep unroll, parallel tail ----------------

__global__ __launch_bounds__(256) void k_agg8(const u32* __restrict__ h8,
                                              const int* __restrict__ rp,
                                              const int* __restrict__ col,
                                              u16* __restrict__ mean) {
    const int lane = threadIdx.x & 63;
    const int node = blockIdx.x * 4 + (threadIdx.x >> 6);
    const int grp  = lane >> 4;
    const int li   = lane & 15;                 // 8B chunk (8 fp8 cols) within 128B row
    const int r0 = rp[node], r1 = rp[node + 1];
    const int deg = r1 - r0;
    const int len = (deg + 3) >> 2;             // chunk per group
    int ge   = r0 + grp * len;
    int gend = ge + len;
    if (gend > r1) gend = r1;

    fltx2 aa[4];
#pragma unroll
    for (int i = 0; i < 4; ++i) aa[i] = (fltx2){0.f, 0.f};

    // 8-deep stage: halves serial latency rounds for high-degree stragglers
    for (; ge + 7 < gend; ge += 8) {
        u32x2 v[8];
#pragma unroll
        for (int i = 0; i < 8; ++i)
            v[i] = *reinterpret_cast<const u32x2*>(&h8[(size_t)col[ge + i] * 32 + li * 2]);
#pragma unroll
        for (int i = 0; i < 8; ++i) add8fp8(aa, v[i]);
    }
    for (; ge + 3 < gend; ge += 4) {
        const int s0 = col[ge], s1 = col[ge + 1], s2 = col[ge + 2], s3 = col[ge + 3];
        const u32x2 v0 = *reinterpret_cast<const u32x2*>(&h8[(size_t)s0 * 32 + li * 2]);
        const u32x2 v1 = *reinterpret_cast<const u32x2*>(&h8[(size_t)s1 * 32 + li * 2]);
        const u32x2 v2 = *reinterpret_cast<const u32x2*>(&h8[(size_t)s2 * 32 + li * 2]);
        const u32x2 v3 = *reinterpret_cast<const u32x2*>(&h8[(size_t)s3 * 32 + li * 2]);
        add8fp8(aa, v0); add8fp8(aa, v1); add8fp8(aa, v2); add8fp8(aa, v3);
    }
    // tail (<=3 edges): issue all loads, then decode
    {
        const int rem = gend - ge;              // 0..3
        u32x2 v0, v1, v2;
        if (rem > 0) v0 = *reinterpret_cast<const u32x2*>(&h8[(size_t)col[ge] * 32 + li * 2]);
        if (rem > 1) v1 = *reinterpret_cast<const u32x2*>(&h8[(size_t)col[ge + 1] * 32 + li * 2]);
        if (rem > 2) v2 = *reinterpret_cast<const u32x2*>(&h8[(size_t)col[ge + 2] * 32 + li * 2]);
        if (rem > 0) add8fp8(aa, v0);
        if (rem > 1) add8fp8(aa, v1);
        if (rem > 2) add8fp8(aa, v2);
    }

    float a[8];
#pragma unroll
    for (int i = 0; i < 4; ++i) { a[i * 2] = aa[i].x; a[i * 2 + 1] = aa[i].y; }
#pragma unroll
    for (int i = 0; i < 8; ++i) {
        a[i] += __shfl_xor(a[i], 16);
        a[i] += __shfl_xor(a[i], 32);
    }
    if (lane < 16) {
        const float inv = 1.0f / fmaxf((float)deg, 1.0f);
        u32x4 o;
        o.x = pack2(a[0] * inv, a[1] * inv);
        o.y = pack2(a[2] * inv, a[3] * inv);
        o.z = pack2(a[4] * inv, a[5] * inv);
        o.w = pack2(a[6] * inv, a[7] * inv);
        __builtin_nontemporal_store(o, reinterpret_cast<u32x4*>(&mean[(size_t)node * HD + (size_t)li * 8]));
    }
}

// ---------------- MFMA GEMM: out = A1@W1 (+ A2@W2) + bias ----------------

template <int A1F32, int RELU, int STATS>
__global__ __launch_bounds__(256) void k_mgemm(
    const void* __restrict__ A1p, const u16* __restrict__ W1T,
    const u16* __restrict__ A2, const u16* __restrict__ W2T,
    const float* __restrict__ bias, u16* __restrict__ out,
    float* __restrict__ stats)
{
    __shared__ u32x4 Wlds[2048];
    const int t    = threadIdx.x;
    const int wv   = t >> 6;
    const int lane = t & 63;
    const int lid  = lane & 15;
    const int kseg = lane >> 4;
    const int row0 = blockIdx.x * 128 + wv * 32;

    f32x4 acc[2][8];
#pragma unroll
    for (int rf = 0; rf < 2; ++rf)
#pragma unroll
        for (int c = 0; c < 8; ++c) acc[rf][c] = (f32x4){0.f, 0.f, 0.f, 0.f};

    int  ar[2];
    bool rok[2];
#pragma unroll
    for (int rf = 0; rf < 2; ++rf) {
        ar[rf]  = row0 + rf * 16 + lid;
        rok[rf] = ar[rf] < NN;
    }

#pragma unroll
    for (int i = 0; i < 8; ++i) {
        const int g   = t + 256 * i;
        const int row = g >> 4;
        const int ch  = g & 15;
        Wlds[row * 16 + (ch ^ (row & 7))] = reinterpret_cast<const u32x4*>(W1T)[g];
    }
    u32x4 wreg[8];
    if (A2 != nullptr) {
#pragma unroll
        for (int i = 0; i < 8; ++i)
            wreg[i] = reinterpret_cast<const u32x4*>(W2T)[t + 256 * i];
    }

    bf16x8 af1[2][4], af2[2][4];
    if (A1F32) {
        const float* A = (const float*)A1p;
#pragma unroll
        for (int rf = 0; rf < 2; ++rf)
#pragma unroll
            for (int kk = 0; kk < 4; ++kk) {
                const int kof = kk * 32 + kseg * 8;
                if (rok[rf]) {
                    const float4 f0 = *reinterpret_cast<const float4*>(&A[(size_t)ar[rf] * HD + kof]);
                    const float4 f1 = *reinterpret_cast<const float4*>(&A[(size_t)ar[rf] * HD + kof + 4]);
                    af1[rf][kk][0] = (short)f2bf(f0.x); af1[rf][kk][1] = (short)f2bf(f0.y);
                    af1[rf][kk][2] = (short)f2bf(f0.z); af1[rf][kk][3] = (short)f2bf(f0.w);
                    af1[rf][kk][4] = (short)f2bf(f1.x); af1[rf][kk][5] = (short)f2bf(f1.y);
                    af1[rf][kk][6] = (short)f2bf(f1.z); af1[rf][kk][7] = (short)f2bf(f1.w);
                } else {
                    af1[rf][kk] = (bf16x8)0;
                }
            }
    } else {
        const u16* A = (const u16*)A1p;
#pragma unroll
        for (int rf = 0; rf < 2; ++rf)
#pragma unroll
            for (int kk = 0; kk < 4; ++kk) {
                const int kof = kk * 32 + kseg * 8;
                af1[rf][kk] = rok[rf]
                    ? *reinterpret_cast<const bf16x8*>(&A[(size_t)ar[rf] * HD + kof])
                    : (bf16x8)0;
            }
    }
    if (A2 != nullptr) {
#pragma unroll
        for (int rf = 0; rf < 2; ++rf)
#pragma unroll
            for (int kk = 0; kk < 4; ++kk) {
                const int kof = kk * 32 + kseg * 8;
                af2[rf][kk] = rok[rf]
                    ? *reinterpret_cast<const bf16x8*>(&A2[(size_t)ar[rf] * HD + kof])
                    : (bf16x8)0;
            }
    }

    __syncthreads();
#pragma unroll
    for (int kk = 0; kk < 4; ++kk) {
#pragma unroll
        for (int c = 0; c < 8; ++c) {
            const int brow = c * 16 + lid;
            const bf16x8 bf = *reinterpret_cast<const bf16x8*>(
                &Wlds[brow * 16 + ((kk * 4 + kseg) ^ (lid & 7))]);
#pragma unroll
            for (int rf = 0; rf < 2; ++rf)
                acc[rf][c] = __builtin_amdgcn_mfma_f32_16x16x32_bf16(af1[rf][kk], bf, acc[rf][c], 0, 0, 0);
        }
    }

    if (A2 != nullptr) {
        __syncthreads();
#pragma unroll
        for (int i = 0; i < 8; ++i) {
            const int g   = t + 256 * i;
            const int row = g >> 4;
            const int ch  = g & 15;
            Wlds[row * 16 + (ch ^ (row & 7))] = wreg[i];
        }
        __syncthreads();
#pragma unroll
        for (int kk = 0; kk < 4; ++kk) {
#pragma unroll
            for (int c = 0; c < 8; ++c) {
                const int brow = c * 16 + lid;
                const bf16x8 bf = *reinterpret_cast<const bf16x8*>(
                    &Wlds[brow * 16 + ((kk * 4 + kseg) ^ (lid & 7))]);
#pragma unroll
                for (int rf = 0; rf < 2; ++rf)
                    acc[rf][c] = __builtin_amdgcn_mfma_f32_16x16x32_bf16(af2[rf][kk], bf, acc[rf][c], 0, 0, 0);
            }
        }
    }

    float bv[8];
#pragma unroll
    for (int c = 0; c < 8; ++c) bv[c] = bias[c * 16 + lid];

    float sv[8], qv[8];
#pragma unroll
    for (int c = 0; c < 8; ++c) { sv[c] = 0.f; qv[c] = 0.f; }

#pragma unroll
    for (int rf = 0; rf < 2; ++rf) {
#pragma unroll
        for (int c = 0; c < 8; ++c) {
            const int colc = c * 16 + lid;
#pragma unroll
            for (int j = 0; j < 4; ++j) {
                const int rrow = row0 + rf * 16 + kseg * 4 + j;
                if (rrow < NN) {
                    float o = acc[rf][c][j] + bv[c];
                    if (RELU) o = fmaxf(o, 0.f);
                    out[(size_t)rrow * HD + colc] = f2bf(o);
                    sv[c] += o;
                    qv[c] += o * o;
                }
            }
        }
    }

    if constexpr (STATS) {
        __shared__ float ls[4][HD], lq[4][HD];
#pragma unroll
        for (int c = 0; c < 8; ++c) {
            sv[c] += __shfl_xor(sv[c], 16);
            sv[c] += __shfl_xor(sv[c], 32);
            qv[c] += __shfl_xor(qv[c], 16);
            qv[c] += __shfl_xor(qv[c], 32);
        }
        if (lane < 16) {
#pragma unroll
            for (int c = 0; c < 8; ++c) {
                ls[wv][c * 16 + lid] = sv[c];
                lq[wv][c * 16 + lid] = qv[c];
            }
        }
        __syncthreads();
        if (t < HD) {
            const float s = (ls[0][t] + ls[1][t]) + (ls[2][t] + ls[3][t]);
            atomicAdd(&stats[t], s);
        } else {
            const int j = t - HD;
            const float q = (lq[0][j] + lq[1][j]) + (lq[2][j] + lq[3][j]);
            atomicAdd(&stats[HD + j], q);
        }
    }
}

// ---------------- fused BN-finalize + relu + residual (+ classifier, + fp8 write) ----------------

template <int CLS>
__global__ __launch_bounds__(256) void k_apply(
    const u16* __restrict__ outb, const float* __restrict__ stats,
    const float* __restrict__ g, const float* __restrict__ bt,
    u16* __restrict__ hb, u32* __restrict__ h8w,
    const float* __restrict__ cw, const float* __restrict__ cb,
    float* __restrict__ logits)
{
    const int t = threadIdx.x;
    const size_t idx4 = (size_t)blockIdx.x * 256 + t;
    const int j = (int)(idx4 & 31) * 4;
    const float4 svv = *reinterpret_cast<const float4*>(&stats[j]);
    const float4 qvv = *reinterpret_cast<const float4*>(&stats[HD + j]);
    const float4 gv  = *reinterpret_cast<const float4*>(&g[j]);
    const float4 bv  = *reinterpret_cast<const float4*>(&bt[j]);
    const float invn = 1.0f / (float)NN;
    float sc[4], sh[4];
    {
        const float sa[4] = {svv.x, svv.y, svv.z, svv.w};
        const float qa[4] = {qvv.x, qvv.y, qvv.z, qvv.w};
        const float ga[4] = {gv.x, gv.y, gv.z, gv.w};
        const float ba[4] = {bv.x, bv.y, bv.z, bv.w};
#pragma unroll
        for (int i = 0; i < 4; ++i) {
            const float mean = sa[i] * invn;
            const float var  = qa[i] * invn - mean * mean;
            sc[i] = ga[i] * rsqrtf(var + EPSI);
            sh[i] = ba[i] - mean * sc[i];
        }
    }
    const uint2 o  = reinterpret_cast<const uint2*>(outb)[idx4];
    const uint2 hv = reinterpret_cast<const uint2*>(hb)[idx4];
    const float r0 = fmaxf(bflo(o.x) * sc[0] + sh[0], 0.f) + bflo(hv.x);
    const float r1 = fmaxf(bfhi(o.x) * sc[1] + sh[1], 0.f) + bfhi(hv.x);
    const float r2 = fmaxf(bflo(o.y) * sc[2] + sh[2], 0.f) + bflo(hv.y);
    const float r3 = fmaxf(bfhi(o.y) * sc[3] + sh[3], 0.f) + bfhi(hv.y);
    reinterpret_cast<uint2*>(hb)[idx4] = make_uint2(pack2(r0, r1), pack2(r2, r3));
    if (h8w != nullptr)
        h8w[idx4] = pk4fp8(r0, r1, r2, r3);

    if constexpr (CLS) {
        const float4 w01 = *reinterpret_cast<const float4*>(&cw[j * 2]);
        const float4 w23 = *reinterpret_cast<const float4*>(&cw[j * 2 + 4]);
        float p0 = r0 * w01.x + r1 * w01.z + r2 * w23.x + r3 * w23.z;
        float p1 = r0 * w01.y + r1 * w01.w + r2 * w23.y + r3 * w23.w;
#pragma unroll
        for (int off = 1; off <= 16; off <<= 1) {
            p0 += __shfl_xor(p0, off);
            p1 += __shfl_xor(p1, off);
        }
        if ((t & 31) == 0) {
            const size_t row = idx4 >> 5;
            logits[row * 2 + 0] = p0 + cb[0];
            logits[row * 2 + 1] = p1 + cb[1];
        }
    }
}

// ---------------- launch ----------------

extern "C" void kernel_launch(void* const* d_in, const int* in_sizes, int n_in,
                              void* d_out, int out_size, void* d_ws, size_t ws_size,
                              hipStream_t stream) {
    const float* x     = (const float*)d_in[0];
    const int*   ei    = (const int*)d_in[1];
    const float* in_w  = (const float*)d_in[2];
    const float* in_b  = (const float*)d_in[3];
    const float* cls_w = (const float*)d_in[4];
    const float* cls_b = (const float*)d_in[5];
    const float* blk_w[3][5];
    for (int bidx = 0; bidx < 3; ++bidx)
        for (int k = 0; k < 5; ++k)
            blk_w[bidx][k] = (const float*)d_in[6 + bidx * 5 + k];

    const int* src = ei;
    const int* dst = ei + NE;

    size_t off = 0;
    auto alloc = [&](size_t bytes) {
        void* p = (char*)d_ws + off;
        off += (bytes + 255) & ~(size_t)255;
        return p;
    };
    u16*   h      = (u16*)alloc((size_t)NN * HD * 2);   // 25.6 MB
    u16*   tmp    = (u16*)alloc((size_t)NN * HD * 2);   // 25.6 MB (binbuf, then mean/pre-BN out)
    int*   rp     = (int*)alloc((size_t)(NN + 1) * 4);
    int*   col    = (int*)alloc((size_t)NE * 4);        // 6.4 MB
    u16*   wtb    = (u16*)alloc((size_t)7 * HD * HD * 2);
    float* stats  = (float*)alloc((size_t)3 * 256 * 4);
    int*   binCur = (int*)alloc((size_t)NRANGE * 4);
    u32*   h8     = (u32*)alloc((size_t)NN * HD);       // 12.8 MB fp8 copy
    const bool useFp8 = (ws_size >= off);
    u32*   binbuf = (u32*)tmp;
    (void)n_in; (void)in_sizes; (void)out_size;

    // transposed bf16 weights (also zeroes stats+binCur)
    WTArgs wa;
    wa.w[0] = in_w;
    for (int bidx = 0; bidx < 3; ++bidx) {
        wa.w[1 + bidx * 2] = blk_w[bidx][0];
        wa.w[2 + bidx * 2] = blk_w[bidx][2];
    }
    for (int m = 0; m < 7; ++m) wa.o[m] = wtb + (size_t)m * HD * HD;
    k_wt<<<dim3(HD, 7), HD, 0, stream>>>(wa, stats, binCur);

    // CSR build
    k_part<<<PART_GRID, 256, 0, stream>>>(src, dst, binCur, binbuf);
    k_fillL2<<<NRANGE, 1024, 0, stream>>>(binCur, binbuf, rp, col);

    const int gemm_grid  = (NN + 127) / 128; // 782
    const int apply_grid = NN * 32 / 256;    // 12500

    // input layer: h = relu(x @ in_w + in_b)
    k_mgemm<1, 1, 0><<<gemm_grid, 256, 0, stream>>>(x, wtb, nullptr, nullptr, in_b, h, nullptr);
    if (useFp8)
        k_h8<<<apply_grid, 256, 0, stream>>>(h, h8);

    for (int bidx = 0; bidx < 3; ++bidx) {
        const u16* lwT = wtb + (size_t)(1 + bidx * 2) * HD * HD;
        const u16* rwT = wtb + (size_t)(2 + bidx * 2) * HD * HD;
        const float* lb = blk_w[bidx][1];
        const float* g  = blk_w[bidx][3];
        const float* bt = blk_w[bidx][4];
        float* st = stats + bidx * 256;

        if (useFp8)
            k_agg8<<<NN / 4, 256, 0, stream>>>(h8, rp, col, tmp);
        else
            k_agg<<<NN / 4, 256, 0, stream>>>(h, rp, col, tmp);

        k_mgemm<0, 0, 1><<<gemm_grid, 256, 0, stream>>>(tmp, lwT, h, rwT, lb, tmp, st);

        u32* h8out = (useFp8 && bidx < 2) ? h8 : nullptr;
        if (bidx < 2)
            k_apply<0><<<apply_grid, 256, 0, stream>>>(tmp, st, g, bt, h, h8out,
                                                       nullptr, nullptr, nullptr);
        else
            k_apply<1><<<apply_grid, 256, 0, stream>>>(tmp, st, g, bt, h, h8out,
                                                       cls_w, cls_b, (float*)d_out);
    }
}